// Round 7
// baseline (171.236 us; speedup 1.0000x reference)
//
#include <hip/hip_runtime.h>

// GCN layer: out = D^-1/2 (A + I) D^-1/2 (X W) + b
// N=50000, E=800000, 128 ch. MFMA bf16 GEMM + fused dinv scaling + bf16 gather table.
// R3: counting-sort CSR build. R4: parallel colscan. R5: agg unroll-4, packed ebuf/csr.
// R6: fused whole CSR build + pack_w into ONE kernel (256 co-resident blocks, manual
//     grid barrier w/ device-scope atomics; counters zeroed by captured memset).
//     agg: masked unroll-8 (MLP 8 incl. tail).

constexpr int CH = 128;
constexpr int NCMAX = 256;     // max coarse buckets (256 nodes each -> N <= 65536)
constexpr int GBLK = 256;      // fused-kernel grid (1 block/CU, co-resident)

typedef __attribute__((ext_vector_type(8))) short short8;
typedef __attribute__((ext_vector_type(4))) float f32x4;

static __device__ __forceinline__ ushort f2bf(float f) {
    unsigned u = __float_as_uint(f);
    u += 0x7fff + ((u >> 16) & 1);   // RNE
    return (ushort)(u >> 16);
}

// co-resident grid barrier: all gridDim.x blocks must be resident (grid <= 256
// one-block-per-CU here). bar[idx] zeroed each launch by captured hipMemsetAsync.
static __device__ __forceinline__ void grid_barrier(int* bar, int idx, int nblk) {
    __syncthreads();
    if (threadIdx.x == 0) {
        __threadfence();   // make prior writes visible at device scope
        __hip_atomic_fetch_add(&bar[idx], 1, __ATOMIC_RELEASE, __HIP_MEMORY_SCOPE_AGENT);
        while (__hip_atomic_load(&bar[idx], __ATOMIC_ACQUIRE, __HIP_MEMORY_SCOPE_AGENT) < nblk)
            __builtin_amdgcn_s_sleep(2);
    }
    __syncthreads();
}

// ---- fused CSR build + W pack -------------------------------------------
// phase1 hist -> phase2 per-bucket colscan -> phase3 bbase scan ->
// phase4 binscatter -> phase5 bucket CSR (+ pack_w on idle blocks)
// h layout: h[bucket * G + block] (transposed -> colscan coalesced)

__global__ __launch_bounds__(256) void fused_csr(const int* __restrict__ src,
        const int* __restrict__ dst, int* __restrict__ h, int* __restrict__ coltot,
        int* __restrict__ bbase, unsigned* __restrict__ ebuf, int* __restrict__ off,
        ushort* __restrict__ csr, float* __restrict__ dinv,
        const float* __restrict__ Wm, ushort* __restrict__ Wp,
        int* __restrict__ bar, int N, int E, int nc) {
    __shared__ int sm[256];
    __shared__ int cur[NCMAX];
    __shared__ int hist2[256];
    int t = threadIdx.x, b = blockIdx.x;
    int G = gridDim.x;
    int chunk = (E + G - 1) / G;
    int s0 = b * chunk, e0 = min(E, s0 + chunk);

    // ---- phase 1: per-chunk histogram over coarse buckets (dst>>8)
    for (int i = t; i < NCMAX; i += 256) cur[i] = 0;
    __syncthreads();
    for (int i = s0 + t; i < e0; i += 256) atomicAdd(&cur[dst[i] >> 8], 1);
    __syncthreads();
    for (int i = t; i < nc; i += 256) h[(size_t)i * G + b] = cur[i];
    grid_barrier(bar, 0, G);

    // ---- phase 2: block b (<nc) scans its bucket's column h[b][0..G)
    if (b < nc) {
        int v = (t < G) ? h[(size_t)b * G + t] : 0;
        sm[t] = v;
        __syncthreads();
        #pragma unroll
        for (int d = 1; d < 256; d <<= 1) {
            int u = (t >= d) ? sm[t - d] : 0;
            __syncthreads();
            sm[t] += u;
            __syncthreads();
        }
        if (t < G) h[(size_t)b * G + t] = sm[t] - v;   // exclusive within column
        if (t == 255) coltot[b] = sm[255];
    }
    grid_barrier(bar, 1, G);

    // ---- phase 3: block 0 scans bucket totals -> bbase
    if (b == 0) {
        int v = (t < nc) ? coltot[t] : 0;
        sm[t] = v;
        __syncthreads();
        #pragma unroll
        for (int d = 1; d < 256; d <<= 1) {
            int u = (t >= d) ? sm[t - d] : 0;
            __syncthreads();
            sm[t] += u;
            __syncthreads();
        }
        if (t < nc) bbase[t] = sm[t] - v;
        if (t == nc - 1) bbase[nc] = sm[t];   // == E
    }
    grid_barrier(bar, 2, G);

    // ---- phase 4: scatter packed (src | (dst&255)<<16) into bucket-sorted ebuf
    for (int i = t; i < nc; i += 256) cur[i] = h[(size_t)i * G + b] + bbase[i];
    __syncthreads();
    for (int i = s0 + t; i < e0; i += 256) {
        int d = dst[i];
        int pos = atomicAdd(&cur[d >> 8], 1);
        ebuf[pos] = (unsigned)src[i] | ((unsigned)(d & 255) << 16);
    }
    grid_barrier(bar, 3, G);

    // ---- phase 5: per-bucket CSR build; idle blocks pack W
    if (b < nc) {
        int s = bbase[b], e = bbase[b + 1];
        hist2[t] = 0;
        __syncthreads();
        for (int i = s + t; i < e; i += 256) atomicAdd(&hist2[(ebuf[i] >> 16) & 255], 1);
        __syncthreads();
        int v = hist2[t];
        sm[t] = v;
        __syncthreads();
        #pragma unroll
        for (int d = 1; d < 256; d <<= 1) {
            int u = (t >= d) ? sm[t - d] : 0;
            __syncthreads();
            sm[t] += u;
            __syncthreads();
        }
        int excl = sm[t] - v;
        int node = b * 256 + t;
        if (node <= N) off[node] = s + excl;
        if (node < N) dinv[node] = rsqrtf((float)(v + 1));   // +1 self loop
        cur[t] = s + excl;
        __syncthreads();
        for (int i = s + t; i < e; i += 256) {
            unsigned u = ebuf[i];
            int pos = atomicAdd(&cur[(u >> 16) & 255], 1);
            csr[pos] = (ushort)(u & 0xffffu);
        }
    } else if (b < nc + 8) {
        // pack W: fp32 [128][128] -> bf16 transposed, XOR-swizzled B-fragments
        int tid = (b - nc) * 256 + t;   // 0..2047
        if (tid < 2048) {
            int col = tid >> 4, ch16 = tid & 15;
            ushort tmp[8];
            #pragma unroll
            for (int i = 0; i < 8; ++i)
                tmp[i] = f2bf(Wm[(size_t)(ch16 * 8 + i) * CH + col]);
            int d = col * 16 + (ch16 ^ (col & 7));
            *(uint4*)&Wp[(size_t)d * 8] = *(uint4*)tmp;
        }
    }
}

// ---- GEMM: xwd[r][:] = (x[r][:] @ W) * dinv[r], bf16 out ----------------

__global__ __launch_bounds__(256) void gemm_mfma(const float* __restrict__ x,
        const ushort* __restrict__ Wp, const float* __restrict__ dinv,
        ushort* __restrict__ xwd, int N) {
    __shared__ alignas(16) ushort Wlds[16384];   // 32 KB
    int t = threadIdx.x;
    int wv = t >> 6, l = t & 63;
    int c15 = l & 15, kc = l >> 4;               // kc in 0..3
    int row0 = blockIdx.x * 64 + wv * 16;
    int r = row0 + c15;
    bool valid = r < N;

    short8 af[4];
    #pragma unroll
    for (int ks = 0; ks < 4; ++ks) {
        float4 a0 = make_float4(0.f,0.f,0.f,0.f), a1 = a0;
        if (valid) {
            const float* p = x + (size_t)r * CH + ks * 32 + kc * 8;
            a0 = *(const float4*)p;
            a1 = *(const float4*)(p + 4);
        }
        short8 v;
        v[0]=f2bf(a0.x); v[1]=f2bf(a0.y); v[2]=f2bf(a0.z); v[3]=f2bf(a0.w);
        v[4]=f2bf(a1.x); v[5]=f2bf(a1.y); v[6]=f2bf(a1.z); v[7]=f2bf(a1.w);
        af[ks] = v;
    }

    #pragma unroll
    for (int i = 0; i < 8; ++i) {
        int idx = i * 256 + t;
        *(uint4*)&Wlds[idx * 8] = *(const uint4*)&Wp[idx * 8];
    }
    __syncthreads();

    f32x4 acc[8];
    #pragma unroll
    for (int ct = 0; ct < 8; ++ct) { f32x4 z = {0.f,0.f,0.f,0.f}; acc[ct] = z; }

    int swz = l & 7;
    #pragma unroll
    for (int ks = 0; ks < 4; ++ks) {
        #pragma unroll
        for (int ct = 0; ct < 8; ++ct) {
            int col = ct * 16 + c15;
            int idx16 = (col * 16 + ks * 4 + kc) ^ swz;
            short8 bfrag = *(const short8*)&Wlds[idx16 * 8];
            acc[ct] = __builtin_amdgcn_mfma_f32_16x16x32_bf16(af[ks], bfrag, acc[ct], 0, 0, 0);
        }
    }

    float dv[4];
    #pragma unroll
    for (int rr = 0; rr < 4; ++rr) {
        int row = row0 + kc * 4 + rr;
        dv[rr] = (row < N) ? dinv[row] : 0.f;
    }
    __syncthreads();   // all waves done reading Wlds; reuse as bounce buffer

    ushort* bw = Wlds + wv * 2048;   // 16 rows x 128 cols bf16 per wave
    #pragma unroll
    for (int ct = 0; ct < 8; ++ct) {
        #pragma unroll
        for (int rr = 0; rr < 4; ++rr) {
            int row_local = kc * 4 + rr;
            bw[row_local * CH + ct * 16 + c15] = f2bf(acc[ct][rr] * dv[rr]);
        }
    }
    #pragma unroll
    for (int p = 0; p < 4; ++p) {
        int row_local = p * 4 + kc;
        int row = row0 + row_local;
        if (row < N) {
            uint4 vv = *(const uint4*)&bw[row_local * CH + c15 * 8];
            *(uint4*)&xwd[(size_t)row * CH + c15 * 8] = vv;
        }
    }
}

// ---- Aggregation: out[i] = dinv[i] * (sum_j xwd[src_j] + xwd[i]) + b ----
// masked unroll-8: 8 concurrent 16B gathers per lane, tail stays in the wide path

__global__ __launch_bounds__(256) void agg_kernel(const ushort* __restrict__ xwd,
        const ushort* __restrict__ csr, const int* __restrict__ off,
        const float* __restrict__ dinv, const float* __restrict__ b,
        float* __restrict__ out, int N) {
    int t = threadIdx.x;
    int c15 = t & 15;                      // 16 lanes/node, 8 ch each
    int node = blockIdx.x * 16 + (t >> 4);
    if (node >= N) return;
    int s = off[node], e = off[node + 1];
    float acc[8] = {0.f,0.f,0.f,0.f,0.f,0.f,0.f,0.f};
    const ushort* base = xwd + c15 * 8;

    int last = e - 1;
    for (int j = s; j < e; j += 8) {
        int idx[8]; float m[8];
        #pragma unroll
        for (int k = 0; k < 8; ++k) {
            int jj = j + k;
            idx[k] = csr[min(jj, last)];
            m[k] = (jj <= last) ? 1.0f : 0.0f;
        }
        uint4 v[8];
        #pragma unroll
        for (int k = 0; k < 8; ++k)
            v[k] = *(const uint4*)(base + (size_t)idx[k] * CH);
        #pragma unroll
        for (int k = 0; k < 8; ++k) {
            acc[0] += m[k] * __uint_as_float(v[k].x << 16);
            acc[1] += m[k] * __uint_as_float(v[k].x & 0xffff0000u);
            acc[2] += m[k] * __uint_as_float(v[k].y << 16);
            acc[3] += m[k] * __uint_as_float(v[k].y & 0xffff0000u);
            acc[4] += m[k] * __uint_as_float(v[k].z << 16);
            acc[5] += m[k] * __uint_as_float(v[k].z & 0xffff0000u);
            acc[6] += m[k] * __uint_as_float(v[k].w << 16);
            acc[7] += m[k] * __uint_as_float(v[k].w & 0xffff0000u);
        }
    }
    {   // self loop term
        uint4 v = *(const uint4*)(base + (size_t)node * CH);
        acc[0] += __uint_as_float(v.x << 16);
        acc[1] += __uint_as_float(v.x & 0xffff0000u);
        acc[2] += __uint_as_float(v.y << 16);
        acc[3] += __uint_as_float(v.y & 0xffff0000u);
        acc[4] += __uint_as_float(v.z << 16);
        acc[5] += __uint_as_float(v.z & 0xffff0000u);
        acc[6] += __uint_as_float(v.w << 16);
        acc[7] += __uint_as_float(v.w & 0xffff0000u);
    }
    float di = dinv[node];
    float4 b0 = *(const float4*)&b[c15 * 8];
    float4 b1 = *(const float4*)&b[c15 * 8 + 4];
    float4 o0, o1;
    o0.x = di * acc[0] + b0.x;  o0.y = di * acc[1] + b0.y;
    o0.z = di * acc[2] + b0.z;  o0.w = di * acc[3] + b0.w;
    o1.x = di * acc[4] + b1.x;  o1.y = di * acc[5] + b1.y;
    o1.z = di * acc[6] + b1.z;  o1.w = di * acc[7] + b1.w;
    float* op = out + (size_t)node * CH + c15 * 8;
    *(float4*)op = o0;
    *(float4*)(op + 4) = o1;
}

// ---- launch -------------------------------------------------------------

extern "C" void kernel_launch(void* const* d_in, const int* in_sizes, int n_in,
                              void* d_out, int out_size, void* d_ws, size_t ws_size,
                              hipStream_t stream) {
    const float* x  = (const float*)d_in[0];
    const float* Wm = (const float*)d_in[1];
    const float* b  = (const float*)d_in[2];
    const int*   ei = (const int*)d_in[3];
    int N = in_sizes[0] / CH;
    int E = in_sizes[3] / 2;
    const int* src = ei;
    const int* dst = ei + E;
    float* out = (float*)d_out;

    char* w = (char*)d_ws;
    auto alloc = [&](size_t bytes) {
        char* p = w;
        w += (bytes + 255) & ~(size_t)255;
        return p;
    };
    int nc = (N + 255) >> 8;                     // 196 coarse buckets

    ushort*   xwd  = (ushort*)alloc((size_t)N * CH * 2);   // 12.8 MB
    unsigned* ebuf = (unsigned*)xwd;                       // E*4 = 3.2 MB, dead before gemm
    int*      off  = (int*)alloc((size_t)(N + 1) * 4);
    ushort*   csr  = (ushort*)alloc((size_t)E * 2);
    float*    dinv = (float*)alloc((size_t)N * 4);
    ushort*   Wp   = (ushort*)alloc((size_t)16384 * 2);
    int*      h    = (int*)alloc((size_t)nc * GBLK * 4);   // 200 KB
    int*      bbase= (int*)alloc((size_t)(nc + 1) * 4);
    int*      coltot=(int*)alloc((size_t)nc * 4);
    int*      bar  = (int*)alloc(4 * sizeof(int));

    hipMemsetAsync(bar, 0, 4 * sizeof(int), stream);   // reset grid barrier each replay
    fused_csr<<<GBLK, 256, 0, stream>>>(src, dst, h, coltot, bbase, ebuf, off, csr,
                                        dinv, Wm, Wp, bar, N, E, nc);
    gemm_mfma<<<(N + 63) / 64, 256, 0, stream>>>(x, Wp, dinv, xwd, N);
    agg_kernel<<<(N + 15) / 16, 256, 0, stream>>>(xwd, csr, off, dinv, b, out, N);
}

// Round 9
// 121.363 us; speedup vs baseline: 1.4109x; 1.4109x over previous
//
#include <hip/hip_runtime.h>

// GCN layer: out = D^-1/2 (A + I) D^-1/2 (X W) + b
// N=50000, E=800000, 128 ch. MFMA bf16 GEMM + fused dinv scaling + bf16 gather table.
// R3: counting-sort CSR build. R4: parallel colscan. R5: packed ebuf/csr.
// R6: agg masked unroll-8 (MLP 8 incl tail) -- kept, measured ~19us.
// R7 FAILED: grid-barrier fused kernel = 130+us (cross-XCD barrier ~30us each).
// R8 FAILED: colscan2 folded bases IN-PLACE into h -> cross-block read/write race
//     (block i reads columns j<i while block j overwrites its column) -> wild
//     scatter positions -> memory fault. R9: colscan2 writes folded bases to a
//     SEPARATE h2 (reads h only, writes h2 only) -- race-free, same structure.

constexpr int CH = 128;
constexpr int CHUNK = 4096;    // edges per binning block
constexpr int NCMAX = 256;     // max coarse buckets (256 nodes each -> N <= 65536)

typedef __attribute__((ext_vector_type(8))) short short8;
typedef __attribute__((ext_vector_type(4))) float f32x4;

static __device__ __forceinline__ ushort f2bf(float f) {
    unsigned u = __float_as_uint(f);
    u += 0x7fff + ((u >> 16) & 1);   // RNE
    return (ushort)(u >> 16);
}

// ---- CSR build: counting sort by destination ----------------------------
// h layout: h[bucket * nblk + block]  (transposed -> colscan coalesced)

__global__ __launch_bounds__(256) void hist_kernel(const int* __restrict__ dst,
        int* __restrict__ h, int E, int nc, int nblk) {
    __shared__ int hh[NCMAX];
    int t = threadIdx.x, b = blockIdx.x;
    for (int i = t; i < NCMAX; i += 256) hh[i] = 0;
    __syncthreads();
    int s = b * CHUNK, e = min(E, s + CHUNK);
    for (int i = s + t; i < e; i += 256) atomicAdd(&hh[dst[i] >> 8], 1);
    __syncthreads();
    for (int i = t; i < nc; i += 256) h[(size_t)i * nblk + b] = hh[i];
}

// block i: bbase_i = sum of columns j<i (redundant, L2-hot, reads h only),
// then scan own column; write folded global bases to h2 (never touches h).
__global__ __launch_bounds__(256) void colscan2(const int* __restrict__ h,
        int* __restrict__ h2, int* __restrict__ bbase, int nblk, int nc) {
    __shared__ int sm[256];
    __shared__ int bb;
    int i = blockIdx.x, t = threadIdx.x;

    int part = 0;
    if (t < nblk)
        for (int j = 0; j < i; ++j) part += h[(size_t)j * nblk + t];
    sm[t] = part;
    __syncthreads();
    #pragma unroll
    for (int d = 128; d > 0; d >>= 1) {
        if (t < d) sm[t] += sm[t + d];
        __syncthreads();
    }
    if (t == 0) bb = sm[0];
    __syncthreads();
    int bbase_i = bb;

    int v = (t < nblk) ? h[(size_t)i * nblk + t] : 0;
    __syncthreads();
    sm[t] = v;
    __syncthreads();
    #pragma unroll
    for (int d = 1; d < 256; d <<= 1) {
        int u = (t >= d) ? sm[t - d] : 0;
        __syncthreads();
        sm[t] += u;
        __syncthreads();
    }
    if (t < nblk) h2[(size_t)i * nblk + t] = sm[t] - v + bbase_i;
    if (t == 0) {
        bbase[i] = bbase_i;
        if (i == nc - 1) bbase[nc] = bbase_i + sm[255];   // == E
    }
}

// scatter packed (src | (dst&255)<<16) into bucket-sorted ebuf; h2 contains
// global exclusive bases for this block's runs
__global__ __launch_bounds__(256) void binscatter_kernel(const int* __restrict__ src,
        const int* __restrict__ dst, const int* __restrict__ h2,
        unsigned* __restrict__ ebuf, int E, int nc, int nblk) {
    __shared__ int cur[NCMAX];
    int t = threadIdx.x, b = blockIdx.x;
    for (int i = t; i < nc; i += 256) cur[i] = h2[(size_t)i * nblk + b];
    __syncthreads();
    int s = b * CHUNK, e = min(E, s + CHUNK);
    for (int i = s + t; i < e; i += 256) {
        int d = dst[i];
        int pos = atomicAdd(&cur[d >> 8], 1);
        ebuf[pos] = (unsigned)src[i] | ((unsigned)(d & 255) << 16);
    }
}

// blocks [0,nc): per-bucket histogram + scan -> off/dinv, scatter src (ushort)
// blocks [nc,nc+8): pack W fp32[128][128] -> bf16 transposed XOR-swizzled
__global__ __launch_bounds__(256) void bucket_csr_packw(const unsigned* __restrict__ ebuf,
        const int* __restrict__ bbase, int* __restrict__ off, ushort* __restrict__ csr,
        float* __restrict__ dinv, const float* __restrict__ Wm, ushort* __restrict__ Wp,
        int N, int nc) {
    __shared__ int hist2[256], cur[256], sm[256];
    int t = threadIdx.x, k = blockIdx.x;
    if (k >= nc) {
        int tid = (k - nc) * 256 + t;   // 0..2047
        if (tid < 2048) {
            int col = tid >> 4, ch16 = tid & 15;
            ushort tmp[8];
            #pragma unroll
            for (int i = 0; i < 8; ++i)
                tmp[i] = f2bf(Wm[(size_t)(ch16 * 8 + i) * CH + col]);
            int d = col * 16 + (ch16 ^ (col & 7));
            *(uint4*)&Wp[(size_t)d * 8] = *(uint4*)tmp;
        }
        return;
    }
    int s = bbase[k], e = bbase[k + 1];
    hist2[t] = 0;
    __syncthreads();
    for (int i = s + t; i < e; i += 256) atomicAdd(&hist2[(ebuf[i] >> 16) & 255], 1);
    __syncthreads();
    int v = hist2[t];
    sm[t] = v;
    __syncthreads();
    #pragma unroll
    for (int d = 1; d < 256; d <<= 1) {
        int u = (t >= d) ? sm[t - d] : 0;
        __syncthreads();
        sm[t] += u;
        __syncthreads();
    }
    int excl = sm[t] - v;
    int node = k * 256 + t;
    if (node <= N) off[node] = s + excl;
    if (node < N) dinv[node] = rsqrtf((float)(v + 1));   // +1 self loop
    cur[t] = s + excl;
    __syncthreads();
    for (int i = s + t; i < e; i += 256) {
        unsigned u = ebuf[i];
        int pos = atomicAdd(&cur[(u >> 16) & 255], 1);
        csr[pos] = (ushort)(u & 0xffffu);
    }
}

// ---- GEMM: xwd[r][:] = (x[r][:] @ W) * dinv[r], bf16 out ----------------

__global__ __launch_bounds__(256) void gemm_mfma(const float* __restrict__ x,
        const ushort* __restrict__ Wp, const float* __restrict__ dinv,
        ushort* __restrict__ xwd, int N) {
    __shared__ alignas(16) ushort Wlds[16384];   // 32 KB
    int t = threadIdx.x;
    int wv = t >> 6, l = t & 63;
    int c15 = l & 15, kc = l >> 4;               // kc in 0..3
    int row0 = blockIdx.x * 64 + wv * 16;
    int r = row0 + c15;
    bool valid = r < N;

    short8 af[4];
    #pragma unroll
    for (int ks = 0; ks < 4; ++ks) {
        float4 a0 = make_float4(0.f,0.f,0.f,0.f), a1 = a0;
        if (valid) {
            const float* p = x + (size_t)r * CH + ks * 32 + kc * 8;
            a0 = *(const float4*)p;
            a1 = *(const float4*)(p + 4);
        }
        short8 v;
        v[0]=f2bf(a0.x); v[1]=f2bf(a0.y); v[2]=f2bf(a0.z); v[3]=f2bf(a0.w);
        v[4]=f2bf(a1.x); v[5]=f2bf(a1.y); v[6]=f2bf(a1.z); v[7]=f2bf(a1.w);
        af[ks] = v;
    }

    #pragma unroll
    for (int i = 0; i < 8; ++i) {
        int idx = i * 256 + t;
        *(uint4*)&Wlds[idx * 8] = *(const uint4*)&Wp[idx * 8];
    }
    __syncthreads();

    f32x4 acc[8];
    #pragma unroll
    for (int ct = 0; ct < 8; ++ct) { f32x4 z = {0.f,0.f,0.f,0.f}; acc[ct] = z; }

    int swz = l & 7;
    #pragma unroll
    for (int ks = 0; ks < 4; ++ks) {
        #pragma unroll
        for (int ct = 0; ct < 8; ++ct) {
            int col = ct * 16 + c15;
            int idx16 = (col * 16 + ks * 4 + kc) ^ swz;
            short8 bfrag = *(const short8*)&Wlds[idx16 * 8];
            acc[ct] = __builtin_amdgcn_mfma_f32_16x16x32_bf16(af[ks], bfrag, acc[ct], 0, 0, 0);
        }
    }

    float dv[4];
    #pragma unroll
    for (int rr = 0; rr < 4; ++rr) {
        int row = row0 + kc * 4 + rr;
        dv[rr] = (row < N) ? dinv[row] : 0.f;
    }
    __syncthreads();   // all waves done reading Wlds; reuse as bounce buffer

    ushort* bw = Wlds + wv * 2048;   // 16 rows x 128 cols bf16 per wave
    #pragma unroll
    for (int ct = 0; ct < 8; ++ct) {
        #pragma unroll
        for (int rr = 0; rr < 4; ++rr) {
            int row_local = kc * 4 + rr;
            bw[row_local * CH + ct * 16 + c15] = f2bf(acc[ct][rr] * dv[rr]);
        }
    }
    #pragma unroll
    for (int p = 0; p < 4; ++p) {
        int row_local = p * 4 + kc;
        int row = row0 + row_local;
        if (row < N) {
            uint4 vv = *(const uint4*)&bw[row_local * CH + c15 * 8];
            *(uint4*)&xwd[(size_t)row * CH + c15 * 8] = vv;
        }
    }
}

// ---- Aggregation: out[i] = dinv[i] * (sum_j xwd[src_j] + xwd[i]) + b ----
// masked unroll-8: 8 concurrent 16B gathers per lane, tail stays in the wide path

__global__ __launch_bounds__(256) void agg_kernel(const ushort* __restrict__ xwd,
        const ushort* __restrict__ csr, const int* __restrict__ off,
        const float* __restrict__ dinv, const float* __restrict__ b,
        float* __restrict__ out, int N) {
    int t = threadIdx.x;
    int c15 = t & 15;                      // 16 lanes/node, 8 ch each
    int node = blockIdx.x * 16 + (t >> 4);
    if (node >= N) return;
    int s = off[node], e = off[node + 1];
    float acc[8] = {0.f,0.f,0.f,0.f,0.f,0.f,0.f,0.f};
    const ushort* base = xwd + c15 * 8;

    int last = e - 1;
    for (int j = s; j < e; j += 8) {
        int idx[8]; float m[8];
        #pragma unroll
        for (int k = 0; k < 8; ++k) {
            int jj = j + k;
            idx[k] = csr[min(jj, last)];
            m[k] = (jj <= last) ? 1.0f : 0.0f;
        }
        uint4 v[8];
        #pragma unroll
        for (int k = 0; k < 8; ++k)
            v[k] = *(const uint4*)(base + (size_t)idx[k] * CH);
        #pragma unroll
        for (int k = 0; k < 8; ++k) {
            acc[0] += m[k] * __uint_as_float(v[k].x << 16);
            acc[1] += m[k] * __uint_as_float(v[k].x & 0xffff0000u);
            acc[2] += m[k] * __uint_as_float(v[k].y << 16);
            acc[3] += m[k] * __uint_as_float(v[k].y & 0xffff0000u);
            acc[4] += m[k] * __uint_as_float(v[k].z << 16);
            acc[5] += m[k] * __uint_as_float(v[k].z & 0xffff0000u);
            acc[6] += m[k] * __uint_as_float(v[k].w << 16);
            acc[7] += m[k] * __uint_as_float(v[k].w & 0xffff0000u);
        }
    }
    {   // self loop term
        uint4 v = *(const uint4*)(base + (size_t)node * CH);
        acc[0] += __uint_as_float(v.x << 16);
        acc[1] += __uint_as_float(v.x & 0xffff0000u);
        acc[2] += __uint_as_float(v.y << 16);
        acc[3] += __uint_as_float(v.y & 0xffff0000u);
        acc[4] += __uint_as_float(v.z << 16);
        acc[5] += __uint_as_float(v.z & 0xffff0000u);
        acc[6] += __uint_as_float(v.w << 16);
        acc[7] += __uint_as_float(v.w & 0xffff0000u);
    }
    float di = dinv[node];
    float4 b0 = *(const float4*)&b[c15 * 8];
    float4 b1 = *(const float4*)&b[c15 * 8 + 4];
    float4 o0, o1;
    o0.x = di * acc[0] + b0.x;  o0.y = di * acc[1] + b0.y;
    o0.z = di * acc[2] + b0.z;  o0.w = di * acc[3] + b0.w;
    o1.x = di * acc[4] + b1.x;  o1.y = di * acc[5] + b1.y;
    o1.z = di * acc[6] + b1.z;  o1.w = di * acc[7] + b1.w;
    float* op = out + (size_t)node * CH + c15 * 8;
    *(float4*)op = o0;
    *(float4*)(op + 4) = o1;
}

// ---- launch -------------------------------------------------------------

extern "C" void kernel_launch(void* const* d_in, const int* in_sizes, int n_in,
                              void* d_out, int out_size, void* d_ws, size_t ws_size,
                              hipStream_t stream) {
    const float* x  = (const float*)d_in[0];
    const float* Wm = (const float*)d_in[1];
    const float* b  = (const float*)d_in[2];
    const int*   ei = (const int*)d_in[3];
    int N = in_sizes[0] / CH;
    int E = in_sizes[3] / 2;
    const int* src = ei;
    const int* dst = ei + E;
    float* out = (float*)d_out;

    char* w = (char*)d_ws;
    auto alloc = [&](size_t bytes) {
        char* p = w;
        w += (bytes + 255) & ~(size_t)255;
        return p;
    };
    int nc = (N + 255) >> 8;                     // 196 coarse buckets
    int nblk = (E + CHUNK - 1) / CHUNK;          // 196 binning blocks

    ushort*   xwd  = (ushort*)alloc((size_t)N * CH * 2);   // 12.8 MB
    unsigned* ebuf = (unsigned*)xwd;                       // E*4 = 3.2 MB, dead before gemm
    int*      off  = (int*)alloc((size_t)(N + 1) * 4);
    ushort*   csr  = (ushort*)alloc((size_t)E * 2);
    float*    dinv = (float*)alloc((size_t)N * 4);
    ushort*   Wp   = (ushort*)alloc((size_t)16384 * 2);
    int*      h    = (int*)alloc((size_t)nc * nblk * 4);   // 154 KB
    int*      h2   = (int*)alloc((size_t)nc * nblk * 4);   // 154 KB
    int*      bbase= (int*)alloc((size_t)(nc + 1) * 4);

    hist_kernel<<<nblk, 256, 0, stream>>>(dst, h, E, nc, nblk);
    colscan2<<<nc, 256, 0, stream>>>(h, h2, bbase, nblk, nc);
    binscatter_kernel<<<nblk, 256, 0, stream>>>(src, dst, h2, ebuf, E, nc, nblk);
    bucket_csr_packw<<<nc + 8, 256, 0, stream>>>(ebuf, bbase, off, csr, dinv, Wm, Wp, N, nc);
    gemm_mfma<<<(N + 63) / 64, 256, 0, stream>>>(x, Wp, dinv, xwd, N);
    agg_kernel<<<(N + 15) / 16, 256, 0, stream>>>(xwd, csr, off, dinv, b, out, N);
}

// Round 11
// 82.325 us; speedup vs baseline: 2.0800x; 1.4742x over previous
//
#include <hip/hip_runtime.h>

// GCN layer: out = D^-1/2 (A + I) D^-1/2 (X W) + b
// N=50000, E=800000, 128 ch. MFMA bf16 GEMM + fused dinv scaling + bf16 gather table.
// R3: counting-sort CSR build. R5: packed ebuf/csr. R6: agg masked unroll-8 (~19us).
// R7 FAILED: grid-barrier fused kernel (cross-XCD barrier ~30us each).
// R8 FAILED: in-place fold raced across blocks -> memory fault.
// R9: colscan2 triangular redundant sum = 48.6us (serial latency-bound loads).
// R10: hist atomicAdds coltot; colscan_cols one-round reduce + own-column fold.
// R11: fix compile -- __builtin_nontemporal_store needs clang ext-vector, not
//      HIP float4. Store via f32x4.

constexpr int CH = 128;
constexpr int CHUNK = 4096;    // edges per binning block
constexpr int NCMAX = 256;     // max coarse buckets (256 nodes each -> N <= 65536)

typedef __attribute__((ext_vector_type(8))) short short8;
typedef __attribute__((ext_vector_type(4))) float f32x4;

static __device__ __forceinline__ ushort f2bf(float f) {
    unsigned u = __float_as_uint(f);
    u += 0x7fff + ((u >> 16) & 1);   // RNE
    return (ushort)(u >> 16);
}

// ---- CSR build: counting sort by destination ----------------------------
// h layout: h[bucket * nblk + block]  (transposed -> colscan coalesced)

__global__ __launch_bounds__(256) void hist_kernel(const int* __restrict__ dst,
        int* __restrict__ h, int* __restrict__ coltot, int E, int nc, int nblk) {
    __shared__ int hh[NCMAX];
    int t = threadIdx.x, b = blockIdx.x;
    for (int i = t; i < NCMAX; i += 256) hh[i] = 0;
    __syncthreads();
    int s = b * CHUNK, e = min(E, s + CHUNK);
    for (int i = s + t * 4; i < e; i += 1024) {
        if (i + 4 <= e) {
            int4 v = *(const int4*)&dst[i];
            atomicAdd(&hh[v.x >> 8], 1);
            atomicAdd(&hh[v.y >> 8], 1);
            atomicAdd(&hh[v.z >> 8], 1);
            atomicAdd(&hh[v.w >> 8], 1);
        } else {
            for (int k = i; k < e; ++k) atomicAdd(&hh[dst[k] >> 8], 1);
        }
    }
    __syncthreads();
    for (int i = t; i < nc; i += 256) {
        int v = hh[i];
        h[(size_t)i * nblk + b] = v;
        if (v) atomicAdd(&coltot[i], v);
    }
}

// block i: bbase_i = reduce(coltot[0..i)) in one parallel round; scan own
// column; write folded global bases in place (own column only -> race-free).
__global__ __launch_bounds__(256) void colscan_cols(int* __restrict__ h,
        const int* __restrict__ coltot, int* __restrict__ bbase, int nblk, int nc) {
    __shared__ int sm[256];
    int i = blockIdx.x, t = threadIdx.x;

    sm[t] = (t < i) ? coltot[t] : 0;    // nc <= 256: one round
    __syncthreads();
    #pragma unroll
    for (int d = 128; d > 0; d >>= 1) {
        if (t < d) sm[t] += sm[t + d];
        __syncthreads();
    }
    int bbase_i = sm[0];
    __syncthreads();

    int v = (t < nblk) ? h[(size_t)i * nblk + t] : 0;
    sm[t] = v;
    __syncthreads();
    #pragma unroll
    for (int d = 1; d < 256; d <<= 1) {
        int u = (t >= d) ? sm[t - d] : 0;
        __syncthreads();
        sm[t] += u;
        __syncthreads();
    }
    if (t < nblk) h[(size_t)i * nblk + t] = sm[t] - v + bbase_i;
    if (t == 0) {
        bbase[i] = bbase_i;
        if (i == nc - 1) bbase[nc] = bbase_i + coltot[i];   // == E
    }
}

// scatter packed (src | (dst&255)<<16) into bucket-sorted ebuf; h contains
// global exclusive bases for this block's runs
__global__ __launch_bounds__(256) void binscatter_kernel(const int* __restrict__ src,
        const int* __restrict__ dst, const int* __restrict__ h,
        unsigned* __restrict__ ebuf, int E, int nc, int nblk) {
    __shared__ int cur[NCMAX];
    int t = threadIdx.x, b = blockIdx.x;
    for (int i = t; i < nc; i += 256) cur[i] = h[(size_t)i * nblk + b];
    __syncthreads();
    int s = b * CHUNK, e = min(E, s + CHUNK);
    for (int i = s + t; i < e; i += 256) {
        int d = dst[i];
        int pos = atomicAdd(&cur[d >> 8], 1);
        ebuf[pos] = (unsigned)src[i] | ((unsigned)(d & 255) << 16);
    }
}

// blocks [0,nc): per-bucket histogram + scan -> off/dinv, scatter src (ushort)
// blocks [nc,nc+8): pack W fp32[128][128] -> bf16 transposed XOR-swizzled
__global__ __launch_bounds__(256) void bucket_csr_packw(const unsigned* __restrict__ ebuf,
        const int* __restrict__ bbase, int* __restrict__ off, ushort* __restrict__ csr,
        float* __restrict__ dinv, const float* __restrict__ Wm, ushort* __restrict__ Wp,
        int N, int nc) {
    __shared__ int hist2[256], cur[256], sm[256];
    int t = threadIdx.x, k = blockIdx.x;
    if (k >= nc) {
        int tid = (k - nc) * 256 + t;   // 0..2047
        if (tid < 2048) {
            int col = tid >> 4, ch16 = tid & 15;
            ushort tmp[8];
            #pragma unroll
            for (int i = 0; i < 8; ++i)
                tmp[i] = f2bf(Wm[(size_t)(ch16 * 8 + i) * CH + col]);
            int d = col * 16 + (ch16 ^ (col & 7));
            *(uint4*)&Wp[(size_t)d * 8] = *(uint4*)tmp;
        }
        return;
    }
    int s = bbase[k], e = bbase[k + 1];
    hist2[t] = 0;
    __syncthreads();
    for (int i = s + t; i < e; i += 256) atomicAdd(&hist2[(ebuf[i] >> 16) & 255], 1);
    __syncthreads();
    int v = hist2[t];
    sm[t] = v;
    __syncthreads();
    #pragma unroll
    for (int d = 1; d < 256; d <<= 1) {
        int u = (t >= d) ? sm[t - d] : 0;
        __syncthreads();
        sm[t] += u;
        __syncthreads();
    }
    int excl = sm[t] - v;
    int node = k * 256 + t;
    if (node <= N) off[node] = s + excl;
    if (node < N) dinv[node] = rsqrtf((float)(v + 1));   // +1 self loop
    cur[t] = s + excl;
    __syncthreads();
    for (int i = s + t; i < e; i += 256) {
        unsigned u = ebuf[i];
        int pos = atomicAdd(&cur[(u >> 16) & 255], 1);
        csr[pos] = (ushort)(u & 0xffffu);
    }
}

// ---- GEMM: xwd[r][:] = (x[r][:] @ W) * dinv[r], bf16 out ----------------

__global__ __launch_bounds__(256) void gemm_mfma(const float* __restrict__ x,
        const ushort* __restrict__ Wp, const float* __restrict__ dinv,
        ushort* __restrict__ xwd, int N) {
    __shared__ alignas(16) ushort Wlds[16384];   // 32 KB
    int t = threadIdx.x;
    int wv = t >> 6, l = t & 63;
    int c15 = l & 15, kc = l >> 4;               // kc in 0..3
    int row0 = blockIdx.x * 64 + wv * 16;
    int r = row0 + c15;
    bool valid = r < N;

    short8 af[4];
    #pragma unroll
    for (int ks = 0; ks < 4; ++ks) {
        float4 a0 = make_float4(0.f,0.f,0.f,0.f), a1 = a0;
        if (valid) {
            const float* p = x + (size_t)r * CH + ks * 32 + kc * 8;
            a0 = *(const float4*)p;
            a1 = *(const float4*)(p + 4);
        }
        short8 v;
        v[0]=f2bf(a0.x); v[1]=f2bf(a0.y); v[2]=f2bf(a0.z); v[3]=f2bf(a0.w);
        v[4]=f2bf(a1.x); v[5]=f2bf(a1.y); v[6]=f2bf(a1.z); v[7]=f2bf(a1.w);
        af[ks] = v;
    }

    #pragma unroll
    for (int i = 0; i < 8; ++i) {
        int idx = i * 256 + t;
        *(uint4*)&Wlds[idx * 8] = *(const uint4*)&Wp[idx * 8];
    }
    __syncthreads();

    f32x4 acc[8];
    #pragma unroll
    for (int ct = 0; ct < 8; ++ct) { f32x4 z = {0.f,0.f,0.f,0.f}; acc[ct] = z; }

    int swz = l & 7;
    #pragma unroll
    for (int ks = 0; ks < 4; ++ks) {
        #pragma unroll
        for (int ct = 0; ct < 8; ++ct) {
            int col = ct * 16 + c15;
            int idx16 = (col * 16 + ks * 4 + kc) ^ swz;
            short8 bfrag = *(const short8*)&Wlds[idx16 * 8];
            acc[ct] = __builtin_amdgcn_mfma_f32_16x16x32_bf16(af[ks], bfrag, acc[ct], 0, 0, 0);
        }
    }

    float dv[4];
    #pragma unroll
    for (int rr = 0; rr < 4; ++rr) {
        int row = row0 + kc * 4 + rr;
        dv[rr] = (row < N) ? dinv[row] : 0.f;
    }
    __syncthreads();   // all waves done reading Wlds; reuse as bounce buffer

    ushort* bw = Wlds + wv * 2048;   // 16 rows x 128 cols bf16 per wave
    #pragma unroll
    for (int ct = 0; ct < 8; ++ct) {
        #pragma unroll
        for (int rr = 0; rr < 4; ++rr) {
            int row_local = kc * 4 + rr;
            bw[row_local * CH + ct * 16 + c15] = f2bf(acc[ct][rr] * dv[rr]);
        }
    }
    #pragma unroll
    for (int p = 0; p < 4; ++p) {
        int row_local = p * 4 + kc;
        int row = row0 + row_local;
        if (row < N) {
            uint4 vv = *(const uint4*)&bw[row_local * CH + c15 * 8];
            *(uint4*)&xwd[(size_t)row * CH + c15 * 8] = vv;
        }
    }
}

// ---- Aggregation: out[i] = dinv[i] * (sum_j xwd[src_j] + xwd[i]) + b ----
// masked unroll-8: 8 concurrent 16B gathers per lane; nontemporal out stores

__global__ __launch_bounds__(256) void agg_kernel(const ushort* __restrict__ xwd,
        const ushort* __restrict__ csr, const int* __restrict__ off,
        const float* __restrict__ dinv, const float* __restrict__ b,
        float* __restrict__ out, int N) {
    int t = threadIdx.x;
    int c15 = t & 15;                      // 16 lanes/node, 8 ch each
    int node = blockIdx.x * 16 + (t >> 4);
    if (node >= N) return;
    int s = off[node], e = off[node + 1];
    float acc[8] = {0.f,0.f,0.f,0.f,0.f,0.f,0.f,0.f};
    const ushort* base = xwd + c15 * 8;

    int last = e - 1;
    for (int j = s; j < e; j += 8) {
        int idx[8]; float m[8];
        #pragma unroll
        for (int k = 0; k < 8; ++k) {
            int jj = j + k;
            idx[k] = csr[min(jj, last)];
            m[k] = (jj <= last) ? 1.0f : 0.0f;
        }
        uint4 v[8];
        #pragma unroll
        for (int k = 0; k < 8; ++k)
            v[k] = *(const uint4*)(base + (size_t)idx[k] * CH);
        #pragma unroll
        for (int k = 0; k < 8; ++k) {
            acc[0] += m[k] * __uint_as_float(v[k].x << 16);
            acc[1] += m[k] * __uint_as_float(v[k].x & 0xffff0000u);
            acc[2] += m[k] * __uint_as_float(v[k].y << 16);
            acc[3] += m[k] * __uint_as_float(v[k].y & 0xffff0000u);
            acc[4] += m[k] * __uint_as_float(v[k].z << 16);
            acc[5] += m[k] * __uint_as_float(v[k].z & 0xffff0000u);
            acc[6] += m[k] * __uint_as_float(v[k].w << 16);
            acc[7] += m[k] * __uint_as_float(v[k].w & 0xffff0000u);
        }
    }
    {   // self loop term
        uint4 v = *(const uint4*)(base + (size_t)node * CH);
        acc[0] += __uint_as_float(v.x << 16);
        acc[1] += __uint_as_float(v.x & 0xffff0000u);
        acc[2] += __uint_as_float(v.y << 16);
        acc[3] += __uint_as_float(v.y & 0xffff0000u);
        acc[4] += __uint_as_float(v.z << 16);
        acc[5] += __uint_as_float(v.z & 0xffff0000u);
        acc[6] += __uint_as_float(v.w << 16);
        acc[7] += __uint_as_float(v.w & 0xffff0000u);
    }
    float di = dinv[node];
    float4 b0 = *(const float4*)&b[c15 * 8];
    float4 b1 = *(const float4*)&b[c15 * 8 + 4];
    f32x4 o0, o1;
    o0[0] = di * acc[0] + b0.x;  o0[1] = di * acc[1] + b0.y;
    o0[2] = di * acc[2] + b0.z;  o0[3] = di * acc[3] + b0.w;
    o1[0] = di * acc[4] + b1.x;  o1[1] = di * acc[5] + b1.y;
    o1[2] = di * acc[6] + b1.z;  o1[3] = di * acc[7] + b1.w;
    float* op = out + (size_t)node * CH + c15 * 8;
    __builtin_nontemporal_store(o0, (f32x4*)op);
    __builtin_nontemporal_store(o1, (f32x4*)(op + 4));
}

// ---- launch -------------------------------------------------------------

extern "C" void kernel_launch(void* const* d_in, const int* in_sizes, int n_in,
                              void* d_out, int out_size, void* d_ws, size_t ws_size,
                              hipStream_t stream) {
    const float* x  = (const float*)d_in[0];
    const float* Wm = (const float*)d_in[1];
    const float* b  = (const float*)d_in[2];
    const int*   ei = (const int*)d_in[3];
    int N = in_sizes[0] / CH;
    int E = in_sizes[3] / 2;
    const int* src = ei;
    const int* dst = ei + E;
    float* out = (float*)d_out;

    char* w = (char*)d_ws;
    auto alloc = [&](size_t bytes) {
        char* p = w;
        w += (bytes + 255) & ~(size_t)255;
        return p;
    };
    int nc = (N + 255) >> 8;                     // 196 coarse buckets
    int nblk = (E + CHUNK - 1) / CHUNK;          // 196 binning blocks

    ushort*   xwd  = (ushort*)alloc((size_t)N * CH * 2);   // 12.8 MB
    unsigned* ebuf = (unsigned*)xwd;                       // E*4 = 3.2 MB, dead before gemm
    int*      off  = (int*)alloc((size_t)(N + 1) * 4);
    ushort*   csr  = (ushort*)alloc((size_t)E * 2);
    float*    dinv = (float*)alloc((size_t)N * 4);
    ushort*   Wp   = (ushort*)alloc((size_t)16384 * 2);
    int*      h    = (int*)alloc((size_t)nc * nblk * 4);   // 154 KB
    int*      bbase= (int*)alloc((size_t)(nc + 1) * 4);
    int*      coltot=(int*)alloc((size_t)nc * 4);

    (void)hipMemsetAsync(coltot, 0, (size_t)nc * 4, stream);   // 784 B, capture-safe
    hist_kernel<<<nblk, 256, 0, stream>>>(dst, h, coltot, E, nc, nblk);
    colscan_cols<<<nc, 256, 0, stream>>>(h, coltot, bbase, nblk, nc);
    binscatter_kernel<<<nblk, 256, 0, stream>>>(src, dst, h, ebuf, E, nc, nblk);
    bucket_csr_packw<<<nc + 8, 256, 0, stream>>>(ebuf, bbase, off, csr, dinv, Wm, Wp, N, nc);
    gemm_mfma<<<(N + 63) / 64, 256, 0, stream>>>(x, Wp, dinv, xwd, N);
    agg_kernel<<<(N + 15) / 16, 256, 0, stream>>>(xwd, csr, off, dinv, b, out, N);
}